// Round 5
// baseline (503.696 us; speedup 1.0000x reference)
//
#include <hip/hip_runtime.h>
#include <hip/hip_bf16.h>
#include <math.h>

typedef __attribute__((ext_vector_type(8))) short short8;
typedef __attribute__((ext_vector_type(4))) float f32x4;

#define C_DIM 1024
#define T_DIM 2048
#define NH 16
#define HD 64
#define NTOK 4096

__device__ __forceinline__ unsigned short f2bf(float f) {
  unsigned u = __float_as_uint(f);
  u += 0x7fffu + ((u >> 16) & 1u);
  return (unsigned short)(u >> 16);
}

// ---------------- LayerNorm: fp32 [rows,1024] -> bf16 ----------------
__global__ __launch_bounds__(256) void ln_kernel(
    const float* __restrict__ x, const float* __restrict__ g,
    const float* __restrict__ b, unsigned short* __restrict__ out) {
  int row = blockIdx.x;
  int tid = threadIdx.x;
  const float4* xr = (const float4*)(x + (size_t)row * C_DIM);
  float4 v = xr[tid];
  float s = v.x + v.y + v.z + v.w;
  float ss = v.x * v.x + v.y * v.y + v.z * v.z + v.w * v.w;
#pragma unroll
  for (int off = 32; off; off >>= 1) {
    s += __shfl_down(s, off);
    ss += __shfl_down(ss, off);
  }
  __shared__ float red[8];
  if ((tid & 63) == 0) { red[tid >> 6] = s; red[4 + (tid >> 6)] = ss; }
  __syncthreads();
  float S = red[0] + red[1] + red[2] + red[3];
  float SS = red[4] + red[5] + red[6] + red[7];
  float mu = S * (1.0f / C_DIM);
  float var = SS * (1.0f / C_DIM) - mu * mu;
  float rs = rsqrtf(var + 1e-5f);
  float4 gg = ((const float4*)g)[tid];
  float4 bb = ((const float4*)b)[tid];
  ushort4 o;
  o.x = f2bf((v.x - mu) * rs * gg.x + bb.x);
  o.y = f2bf((v.y - mu) * rs * gg.y + bb.y);
  o.z = f2bf((v.z - mu) * rs * gg.z + bb.z);
  o.w = f2bf((v.w - mu) * rs * gg.w + bb.w);
  *(ushort4*)(out + (size_t)row * C_DIM + tid * 4) = o;
}

// ------------- weight transpose+cast: W[K][N] fp32 -> Wt[N][K] bf16 -------------
__global__ __launch_bounds__(256) void wt_kernel(
    const float* __restrict__ W, unsigned short* __restrict__ Wt, int K, int N) {
  __shared__ float t[32][33];
  int n0 = blockIdx.x * 32, k0 = blockIdx.y * 32;
  int tx = threadIdx.x, ty = threadIdx.y;
#pragma unroll
  for (int j = 0; j < 4; j++)
    t[ty + j * 8][tx] = W[(size_t)(k0 + ty + j * 8) * N + n0 + tx];
  __syncthreads();
#pragma unroll
  for (int j = 0; j < 4; j++)
    Wt[(size_t)(n0 + ty + j * 8) * K + k0 + tx] = f2bf(t[tx][ty + j * 8]);
}

// ------------- V transpose: qkv V slice -> Vt[hb][d][t] bf16 -------------
__global__ __launch_bounds__(256) void vt_kernel(
    const unsigned short* __restrict__ qkv, unsigned short* __restrict__ Vt) {
  __shared__ unsigned short t[32][34];
  int hb = blockIdx.z, bb = hb >> 4, h = hb & 15;
  int t0 = blockIdx.x * 32, d0 = blockIdx.y * 32;
  int tx = threadIdx.x, ty = threadIdx.y;
#pragma unroll
  for (int j = 0; j < 4; j++)
    t[ty + j * 8][tx] =
        qkv[(size_t)(bb * T_DIM + t0 + ty + j * 8) * 3072 + 2048 + h * HD + d0 + tx];
  __syncthreads();
#pragma unroll
  for (int j = 0; j < 4; j++)
    Vt[((size_t)hb * HD + d0 + ty + j * 8) * T_DIM + t0 + tx] = t[tx][ty + j * 8];
}

// ------------- GEMM (register-prefetch pipeline): C = act(A*Bt^T+bias)(+res) -------------
template <int ACT, int OUTBF>
__global__ __launch_bounds__(256) void gemm_bt(
    const unsigned short* __restrict__ A, const unsigned short* __restrict__ Bt,
    const float* __restrict__ bias, const float* __restrict__ res,
    void* __restrict__ Cout, int M, int N, int K) {
  __shared__ short sA[128 * 32];
  __shared__ short sB[128 * 32];
  int tid = threadIdx.x;
  int wave = tid >> 6, lane = tid & 63;
  int l16 = lane & 15, quad = lane >> 4;
  int row0 = blockIdx.y * 128, col0 = blockIdx.x * 128;
  int wm = (wave & 1) * 64, wn = (wave >> 1) * 64;
  f32x4 acc[4][4];
#pragma unroll
  for (int i = 0; i < 4; i++)
#pragma unroll
    for (int j = 0; j < 4; j++) acc[i][j] = (f32x4){0.f, 0.f, 0.f, 0.f};

  int r1 = tid >> 2, cc1 = (tid & 3) * 8;
  const unsigned short* Ap = A + (size_t)(row0 + r1) * K + cc1;
  const unsigned short* Bp = Bt + (size_t)(col0 + r1) * K + cc1;
  const size_t RSK = (size_t)64 * K;
  uint4 pa0 = *(const uint4*)Ap;
  uint4 pa1 = *(const uint4*)(Ap + RSK);
  uint4 pb0 = *(const uint4*)Bp;
  uint4 pb1 = *(const uint4*)(Bp + RSK);

  for (int k0 = 0; k0 < K; k0 += 32) {
    if (k0) __syncthreads();
    *(uint4*)&sA[r1 * 32 + cc1] = pa0;
    *(uint4*)&sA[(r1 + 64) * 32 + cc1] = pa1;
    *(uint4*)&sB[r1 * 32 + cc1] = pb0;
    *(uint4*)&sB[(r1 + 64) * 32 + cc1] = pb1;
    __syncthreads();
    if (k0 + 32 < K) {
      pa0 = *(const uint4*)(Ap + k0 + 32);
      pa1 = *(const uint4*)(Ap + RSK + k0 + 32);
      pb0 = *(const uint4*)(Bp + k0 + 32);
      pb1 = *(const uint4*)(Bp + RSK + k0 + 32);
    }
    short8 a[4], b[4];
#pragma unroll
    for (int i = 0; i < 4; i++) {
      a[i] = *(const short8*)&sA[(wm + i * 16 + l16) * 32 + quad * 8];
      b[i] = *(const short8*)&sB[(wn + i * 16 + l16) * 32 + quad * 8];
    }
#pragma unroll
    for (int mi = 0; mi < 4; mi++)
#pragma unroll
      for (int ni = 0; ni < 4; ni++)
        acc[mi][ni] = __builtin_amdgcn_mfma_f32_16x16x32_bf16(a[mi], b[ni], acc[mi][ni], 0, 0, 0);
  }
#pragma unroll
  for (int mi = 0; mi < 4; mi++) {
#pragma unroll
    for (int ni = 0; ni < 4; ni++) {
      int col = col0 + wn + ni * 16 + l16;
      float bv = bias[col];
#pragma unroll
      for (int i = 0; i < 4; i++) {
        int row = row0 + wm + mi * 16 + quad * 4 + i;
        float v = acc[mi][ni][i] + bv;
        if (ACT == 1) v = 0.5f * v * (1.0f + erff(v * 0.7071067811865475f));
        if (res) v += res[(size_t)row * N + col];
        if (OUTBF)
          ((unsigned short*)Cout)[(size_t)row * N + col] = f2bf(v);
        else
          ((float*)Cout)[(size_t)row * N + col] = v;
      }
    }
  }
}

// ------------- barrier-free MFMA causal flash attention -------------
// 2 waves/block, each wave independent: 16 q rows, KV tiles of 32.
// K/V fragments load global->register directly (L2-resident);
// only P round-trips through tiny wave-private LDS. No __syncthreads.
// Balance: wave 0 -> q-tile bx, wave 1 -> q-tile 127-bx (constant block work).
__global__ __launch_bounds__(128) void attn_mfma_kernel(
    const unsigned short* __restrict__ qkv, const unsigned short* __restrict__ Vt,
    unsigned short* __restrict__ Y) {
  __shared__ short sP[2][16 * 36];
  int hb = blockIdx.y, bb = hb >> 4, h = hb & 15;
  int tid = threadIdx.x, wave = tid >> 6, lane = tid & 63;
  int l16 = lane & 15, quad = lane >> 4;
  int qidx = wave ? (127 - (int)blockIdx.x) : (int)blockIdx.x;
  int qbase = qidx * 16;
  int ntiles = (qidx >> 1) + 1;

  const unsigned short* qrow = qkv + (size_t)(bb * T_DIM + qbase + l16) * 3072 + h * HD;
  short8 qf[2];
  qf[0] = *(const short8*)(qrow + quad * 8);
  qf[1] = *(const short8*)(qrow + 32 + quad * 8);

  const unsigned short* Kb = qkv + (size_t)bb * T_DIM * 3072 + C_DIM + h * HD;  // K[t][d]
  const unsigned short* Vb = Vt + (size_t)hb * HD * T_DIM;                      // Vt[d][t]

  f32x4 o[4];
#pragma unroll
  for (int i = 0; i < 4; i++) o[i] = (f32x4){0.f, 0.f, 0.f, 0.f};
  float m = -1e30f, l = 0.f;

  short8 ck[4], cv[4];
#pragma unroll
  for (int mt = 0; mt < 2; mt++)
#pragma unroll
    for (int kc = 0; kc < 2; kc++)
      ck[mt * 2 + kc] =
          *(const short8*)(Kb + (size_t)(mt * 16 + l16) * 3072 + kc * 32 + quad * 8);
#pragma unroll
  for (int dt = 0; dt < 4; dt++)
    cv[dt] = *(const short8*)(Vb + (size_t)(dt * 16 + l16) * T_DIM + quad * 8);

  for (int kt = 0; kt < ntiles; kt++) {
    int kv0 = kt * 32;
    short8 nk[4], nv[4];
    if (kt + 1 < ntiles) {  // prefetch next KV tile into registers
      int nv0 = kv0 + 32;
#pragma unroll
      for (int mt = 0; mt < 2; mt++)
#pragma unroll
        for (int kc = 0; kc < 2; kc++)
          nk[mt * 2 + kc] = *(const short8*)(Kb + (size_t)(nv0 + mt * 16 + l16) * 3072 +
                                             kc * 32 + quad * 8);
#pragma unroll
      for (int dt = 0; dt < 4; dt++)
        nv[dt] = *(const short8*)(Vb + (size_t)(dt * 16 + l16) * T_DIM + nv0 + quad * 8);
    }

    // ---- S^T = K·Q^T : M=kv(32), N=q(16), K=d(64) ----
    f32x4 st[2];
    st[0] = (f32x4){0.f, 0.f, 0.f, 0.f};
    st[1] = (f32x4){0.f, 0.f, 0.f, 0.f};
#pragma unroll
    for (int kc = 0; kc < 2; kc++)
#pragma unroll
      for (int mt = 0; mt < 2; mt++)
        st[mt] = __builtin_amdgcn_mfma_f32_16x16x32_bf16(ck[mt * 2 + kc], qf[kc], st[mt], 0, 0, 0);

    // ---- online softmax (mask only on last tile) ----
    float vals[8];
    if (kt == ntiles - 1) {
      int qg = qbase + l16;
#pragma unroll
      for (int mt = 0; mt < 2; mt++)
#pragma unroll
        for (int r = 0; r < 4; r++) {
          int kv = kv0 + mt * 16 + quad * 4 + r;
          vals[mt * 4 + r] = (kv <= qg) ? st[mt][r] * 0.125f : -1e30f;
        }
    } else {
#pragma unroll
      for (int mt = 0; mt < 2; mt++)
#pragma unroll
        for (int r = 0; r < 4; r++) vals[mt * 4 + r] = st[mt][r] * 0.125f;
    }
    float mx = vals[0];
#pragma unroll
    for (int i = 1; i < 8; i++) mx = fmaxf(mx, vals[i]);
    mx = fmaxf(mx, __shfl_xor(mx, 16));
    mx = fmaxf(mx, __shfl_xor(mx, 32));
    float mnew = fmaxf(m, mx);
    float alpha = __expf(m - mnew);
    float ps = 0.f;
#pragma unroll
    for (int i = 0; i < 8; i++) {
      vals[i] = __expf(vals[i] - mnew);
      ps += vals[i];
    }
    ps += __shfl_xor(ps, 16);
    ps += __shfl_xor(ps, 32);
    l = l * alpha + ps;
    m = mnew;
#pragma unroll
    for (int r = 0; r < 4; r++) {
      float ar = __shfl(alpha, quad * 20 + r);
#pragma unroll
      for (int dt = 0; dt < 4; dt++) o[dt][r] *= ar;
    }

    // ---- P[q][kv] via wave-private LDS (C-layout -> A-layout) ----
#pragma unroll
    for (int mt = 0; mt < 2; mt++) {
      ushort4 pw;
      pw.x = f2bf(vals[mt * 4 + 0]);
      pw.y = f2bf(vals[mt * 4 + 1]);
      pw.z = f2bf(vals[mt * 4 + 2]);
      pw.w = f2bf(vals[mt * 4 + 3]);
      *(ushort4*)&sP[wave][l16 * 36 + mt * 16 + quad * 4] = pw;
    }
    short8 pa = *(const short8*)&sP[wave][l16 * 36 + quad * 8];
#pragma unroll
    for (int dt = 0; dt < 4; dt++)
      o[dt] = __builtin_amdgcn_mfma_f32_16x16x32_bf16(pa, cv[dt], o[dt], 0, 0, 0);
#pragma unroll
    for (int i = 0; i < 4; i++) {
      ck[i] = nk[i];
      cv[i] = nv[i];
    }
  }

  float il[4];
#pragma unroll
  for (int r = 0; r < 4; r++) il[r] = 1.0f / __shfl(l, quad * 20 + r);
  unsigned short* Yb = Y + (size_t)(bb * T_DIM + qbase) * C_DIM + h * HD;
#pragma unroll
  for (int dt = 0; dt < 4; dt++)
#pragma unroll
    for (int r = 0; r < 4; r++)
      Yb[(size_t)(quad * 4 + r) * C_DIM + dt * 16 + l16] = f2bf(o[dt][r] * il[r]);
}

extern "C" void kernel_launch(void* const* d_in, const int* in_sizes, int n_in,
                              void* d_out, int out_size, void* d_ws, size_t ws_size,
                              hipStream_t stream) {
  const float* x      = (const float*)d_in[0];
  const float* ln1_g  = (const float*)d_in[1];
  const float* ln1_b  = (const float*)d_in[2];
  const float* attn_w = (const float*)d_in[3];
  const float* attn_b = (const float*)d_in[4];
  const float* proj_w = (const float*)d_in[5];
  const float* proj_b = (const float*)d_in[6];
  const float* ln2_g  = (const float*)d_in[7];
  const float* ln2_b  = (const float*)d_in[8];
  const float* fc_w   = (const float*)d_in[9];
  const float* fc_b   = (const float*)d_in[10];
  const float* fc2_w  = (const float*)d_in[11];
  const float* fc2_b  = (const float*)d_in[12];

  char* ws = (char*)d_ws;
  unsigned short* wqkv_t  = (unsigned short*)(ws + 0);          // 6 MB
  unsigned short* wproj_t = (unsigned short*)(ws + 6291456);    // 2 MB
  unsigned short* wfc_t   = (unsigned short*)(ws + 8388608);    // 8 MB
  unsigned short* wfc2_t  = (unsigned short*)(ws + 16777216);   // 8 MB
  unsigned short* xn1     = (unsigned short*)(ws + 25165824);   // 8 MB (reused as xn2)
  unsigned short* qkv     = (unsigned short*)(ws + 33554432);   // 24 MB (32M..56M)
  unsigned short* y       = (unsigned short*)(ws + 58720256);   // 8 MB (56M..64M)
  unsigned short* Vtb     = (unsigned short*)(ws + 67108864);   // 8 MB (64M..72M)
  unsigned short* hmid    = (unsigned short*)(ws + 33554432);   // 32 MB, aliases qkv+y (dead)
  unsigned short* xn2     = xn1;
  float* x1  = (float*)d_out;
  float* out = (float*)d_out;

  dim3 t32x8(32, 8);
  wt_kernel<<<dim3(3072 / 32, 1024 / 32), t32x8, 0, stream>>>(attn_w, wqkv_t, 1024, 3072);
  wt_kernel<<<dim3(1024 / 32, 1024 / 32), t32x8, 0, stream>>>(proj_w, wproj_t, 1024, 1024);
  wt_kernel<<<dim3(4096 / 32, 1024 / 32), t32x8, 0, stream>>>(fc_w, wfc_t, 1024, 4096);
  wt_kernel<<<dim3(1024 / 32, 4096 / 32), t32x8, 0, stream>>>(fc2_w, wfc2_t, 4096, 1024);

  ln_kernel<<<NTOK, 256, 0, stream>>>(x, ln1_g, ln1_b, xn1);
  gemm_bt<0, 1><<<dim3(3072 / 128, NTOK / 128), 256, 0, stream>>>(
      xn1, wqkv_t, attn_b, nullptr, qkv, NTOK, 3072, 1024);
  vt_kernel<<<dim3(T_DIM / 32, HD / 32, 32), t32x8, 0, stream>>>(qkv, Vtb);
  attn_mfma_kernel<<<dim3(128 / 2, 32), 128, 0, stream>>>(qkv, Vtb, y);
  gemm_bt<0, 0><<<dim3(1024 / 128, NTOK / 128), 256, 0, stream>>>(
      y, wproj_t, proj_b, x, (void*)x1, NTOK, 1024, 1024);
  ln_kernel<<<NTOK, 256, 0, stream>>>(x1, ln2_g, ln2_b, xn2);
  gemm_bt<1, 1><<<dim3(4096 / 128, NTOK / 128), 256, 0, stream>>>(
      xn2, wfc_t, fc_b, nullptr, hmid, NTOK, 4096, 1024);
  gemm_bt<0, 0><<<dim3(1024 / 128, NTOK / 128), 256, 0, stream>>>(
      hmid, wfc2_t, fc2_b, x1, (void*)out, NTOK, 1024, 4096);
}

// Round 6
// 399.783 us; speedup vs baseline: 1.2599x; 1.2599x over previous
//
#include <hip/hip_runtime.h>
#include <hip/hip_bf16.h>
#include <math.h>

typedef __attribute__((ext_vector_type(8))) short short8;
typedef __attribute__((ext_vector_type(4))) float f32x4;

#define C_DIM 1024
#define T_DIM 2048
#define NH 16
#define HD 64
#define NTOK 4096

__device__ __forceinline__ unsigned short f2bf(float f) {
  unsigned u = __float_as_uint(f);
  u += 0x7fffu + ((u >> 16) & 1u);
  return (unsigned short)(u >> 16);
}

// ---------------- LayerNorm: fp32 [rows,1024] -> bf16 ----------------
__global__ __launch_bounds__(256) void ln_kernel(
    const float* __restrict__ x, const float* __restrict__ g,
    const float* __restrict__ b, unsigned short* __restrict__ out) {
  int row = blockIdx.x;
  int tid = threadIdx.x;
  const float4* xr = (const float4*)(x + (size_t)row * C_DIM);
  float4 v = xr[tid];
  float s = v.x + v.y + v.z + v.w;
  float ss = v.x * v.x + v.y * v.y + v.z * v.z + v.w * v.w;
#pragma unroll
  for (int off = 32; off; off >>= 1) {
    s += __shfl_down(s, off);
    ss += __shfl_down(ss, off);
  }
  __shared__ float red[8];
  if ((tid & 63) == 0) { red[tid >> 6] = s; red[4 + (tid >> 6)] = ss; }
  __syncthreads();
  float S = red[0] + red[1] + red[2] + red[3];
  float SS = red[4] + red[5] + red[6] + red[7];
  float mu = S * (1.0f / C_DIM);
  float var = SS * (1.0f / C_DIM) - mu * mu;
  float rs = rsqrtf(var + 1e-5f);
  float4 gg = ((const float4*)g)[tid];
  float4 bb = ((const float4*)b)[tid];
  ushort4 o;
  o.x = f2bf((v.x - mu) * rs * gg.x + bb.x);
  o.y = f2bf((v.y - mu) * rs * gg.y + bb.y);
  o.z = f2bf((v.z - mu) * rs * gg.z + bb.z);
  o.w = f2bf((v.w - mu) * rs * gg.w + bb.w);
  *(ushort4*)(out + (size_t)row * C_DIM + tid * 4) = o;
}

// ------------- weight transpose+cast: W[K][N] fp32 -> Wt[N][K] bf16 -------------
__global__ __launch_bounds__(256) void wt_kernel(
    const float* __restrict__ W, unsigned short* __restrict__ Wt, int K, int N) {
  __shared__ float t[32][33];
  int n0 = blockIdx.x * 32, k0 = blockIdx.y * 32;
  int tx = threadIdx.x, ty = threadIdx.y;
#pragma unroll
  for (int j = 0; j < 4; j++)
    t[ty + j * 8][tx] = W[(size_t)(k0 + ty + j * 8) * N + n0 + tx];
  __syncthreads();
#pragma unroll
  for (int j = 0; j < 4; j++)
    Wt[(size_t)(n0 + ty + j * 8) * K + k0 + tx] = f2bf(t[tx][ty + j * 8]);
}

// ------------- GEMM 128x128 (register-prefetch): C = act(A*Bt^T+bias)(+res) -------------
template <int ACT, int OUTBF>
__global__ __launch_bounds__(256) void gemm_bt(
    const unsigned short* __restrict__ A, const unsigned short* __restrict__ Bt,
    const float* __restrict__ bias, const float* __restrict__ res,
    void* __restrict__ Cout, int M, int N, int K) {
  __shared__ short sA[128 * 32];
  __shared__ short sB[128 * 32];
  int tid = threadIdx.x;
  int wave = tid >> 6, lane = tid & 63;
  int l16 = lane & 15, quad = lane >> 4;
  int row0 = blockIdx.y * 128, col0 = blockIdx.x * 128;
  int wm = (wave & 1) * 64, wn = (wave >> 1) * 64;
  f32x4 acc[4][4];
#pragma unroll
  for (int i = 0; i < 4; i++)
#pragma unroll
    for (int j = 0; j < 4; j++) acc[i][j] = (f32x4){0.f, 0.f, 0.f, 0.f};

  int r1 = tid >> 2, cc1 = (tid & 3) * 8;
  const unsigned short* Ap = A + (size_t)(row0 + r1) * K + cc1;
  const unsigned short* Bp = Bt + (size_t)(col0 + r1) * K + cc1;
  const size_t RSK = (size_t)64 * K;
  uint4 pa0 = *(const uint4*)Ap;
  uint4 pa1 = *(const uint4*)(Ap + RSK);
  uint4 pb0 = *(const uint4*)Bp;
  uint4 pb1 = *(const uint4*)(Bp + RSK);

  for (int k0 = 0; k0 < K; k0 += 32) {
    if (k0) __syncthreads();
    *(uint4*)&sA[r1 * 32 + cc1] = pa0;
    *(uint4*)&sA[(r1 + 64) * 32 + cc1] = pa1;
    *(uint4*)&sB[r1 * 32 + cc1] = pb0;
    *(uint4*)&sB[(r1 + 64) * 32 + cc1] = pb1;
    __syncthreads();
    if (k0 + 32 < K) {
      pa0 = *(const uint4*)(Ap + k0 + 32);
      pa1 = *(const uint4*)(Ap + RSK + k0 + 32);
      pb0 = *(const uint4*)(Bp + k0 + 32);
      pb1 = *(const uint4*)(Bp + RSK + k0 + 32);
    }
    short8 a[4], b[4];
#pragma unroll
    for (int i = 0; i < 4; i++) {
      a[i] = *(const short8*)&sA[(wm + i * 16 + l16) * 32 + quad * 8];
      b[i] = *(const short8*)&sB[(wn + i * 16 + l16) * 32 + quad * 8];
    }
#pragma unroll
    for (int mi = 0; mi < 4; mi++)
#pragma unroll
      for (int ni = 0; ni < 4; ni++)
        acc[mi][ni] = __builtin_amdgcn_mfma_f32_16x16x32_bf16(a[mi], b[ni], acc[mi][ni], 0, 0, 0);
  }
#pragma unroll
  for (int mi = 0; mi < 4; mi++) {
#pragma unroll
    for (int ni = 0; ni < 4; ni++) {
      int col = col0 + wn + ni * 16 + l16;
      float bv = bias[col];
#pragma unroll
      for (int i = 0; i < 4; i++) {
        int row = row0 + wm + mi * 16 + quad * 4 + i;
        float v = acc[mi][ni][i] + bv;
        if (ACT == 1) v = 0.5f * v * (1.0f + erff(v * 0.7071067811865475f));
        if (res) v += res[(size_t)row * N + col];
        if (OUTBF)
          ((unsigned short*)Cout)[(size_t)row * N + col] = f2bf(v);
        else
          ((float*)Cout)[(size_t)row * N + col] = v;
      }
    }
  }
}

// ------------- GEMM 128x64 (for N=1024: 512 blocks -> 2/CU latency overlap) -------------
template <int ACT, int OUTBF>
__global__ __launch_bounds__(256) void gemm_bt64(
    const unsigned short* __restrict__ A, const unsigned short* __restrict__ Bt,
    const float* __restrict__ bias, const float* __restrict__ res,
    void* __restrict__ Cout, int M, int N, int K) {
  __shared__ short sA[128 * 32];
  __shared__ short sB[64 * 32];
  int tid = threadIdx.x;
  int wave = tid >> 6, lane = tid & 63;
  int l16 = lane & 15, quad = lane >> 4;
  int row0 = blockIdx.y * 128, col0 = blockIdx.x * 64;
  int wm = (wave & 1) * 64, wn = (wave >> 1) * 32;
  f32x4 acc[4][2];
#pragma unroll
  for (int i = 0; i < 4; i++)
#pragma unroll
    for (int j = 0; j < 2; j++) acc[i][j] = (f32x4){0.f, 0.f, 0.f, 0.f};

  int r1 = tid >> 2, cc1 = (tid & 3) * 8;
  const unsigned short* Ap = A + (size_t)(row0 + r1) * K + cc1;
  const unsigned short* Bp = Bt + (size_t)(col0 + r1) * K + cc1;
  const size_t RSK = (size_t)64 * K;
  uint4 pa0 = *(const uint4*)Ap;
  uint4 pa1 = *(const uint4*)(Ap + RSK);
  uint4 pb0 = *(const uint4*)Bp;

  for (int k0 = 0; k0 < K; k0 += 32) {
    if (k0) __syncthreads();
    *(uint4*)&sA[r1 * 32 + cc1] = pa0;
    *(uint4*)&sA[(r1 + 64) * 32 + cc1] = pa1;
    *(uint4*)&sB[r1 * 32 + cc1] = pb0;
    __syncthreads();
    if (k0 + 32 < K) {
      pa0 = *(const uint4*)(Ap + k0 + 32);
      pa1 = *(const uint4*)(Ap + RSK + k0 + 32);
      pb0 = *(const uint4*)(Bp + k0 + 32);
    }
    short8 a[4], b[2];
#pragma unroll
    for (int i = 0; i < 4; i++)
      a[i] = *(const short8*)&sA[(wm + i * 16 + l16) * 32 + quad * 8];
#pragma unroll
    for (int i = 0; i < 2; i++)
      b[i] = *(const short8*)&sB[(wn + i * 16 + l16) * 32 + quad * 8];
#pragma unroll
    for (int mi = 0; mi < 4; mi++)
#pragma unroll
      for (int ni = 0; ni < 2; ni++)
        acc[mi][ni] = __builtin_amdgcn_mfma_f32_16x16x32_bf16(a[mi], b[ni], acc[mi][ni], 0, 0, 0);
  }
#pragma unroll
  for (int mi = 0; mi < 4; mi++) {
#pragma unroll
    for (int ni = 0; ni < 2; ni++) {
      int col = col0 + wn + ni * 16 + l16;
      float bv = bias[col];
#pragma unroll
      for (int i = 0; i < 4; i++) {
        int row = row0 + wm + mi * 16 + quad * 4 + i;
        float v = acc[mi][ni][i] + bv;
        if (ACT == 1) v = 0.5f * v * (1.0f + erff(v * 0.7071067811865475f));
        if (res) v += res[(size_t)row * N + col];
        if (OUTBF)
          ((unsigned short*)Cout)[(size_t)row * N + col] = f2bf(v);
        else
          ((float*)Cout)[(size_t)row * N + col] = v;
      }
    }
  }
}

// ------------- MFMA causal flash attention, paired q-tiles, shared KV staging -------------
#define AP 72
struct AttnState {
  f32x4 o[4];
  float m, l;
};

__device__ __forceinline__ void attn_tile_compute(
    const short* __restrict__ sK, const short* __restrict__ sVt,
    short* __restrict__ sPw, const short8* qf, int qg, int kv0, int diag,
    AttnState& S, int l16, int quad) {
  // S^T = K·Q^T : M=kv(64), N=q(16), K=d(64)
  f32x4 st[4];
#pragma unroll
  for (int i = 0; i < 4; i++) st[i] = (f32x4){0.f, 0.f, 0.f, 0.f};
#pragma unroll
  for (int kc = 0; kc < 2; kc++)
#pragma unroll
    for (int mt = 0; mt < 4; mt++) {
      short8 af = *(const short8*)&sK[(mt * 16 + l16) * AP + kc * 32 + quad * 8];
      st[mt] = __builtin_amdgcn_mfma_f32_16x16x32_bf16(af, qf[kc], st[mt], 0, 0, 0);
    }
  float vals[16];
  if (diag) {
#pragma unroll
    for (int mt = 0; mt < 4; mt++)
#pragma unroll
      for (int r = 0; r < 4; r++) {
        int kv = kv0 + mt * 16 + quad * 4 + r;
        vals[mt * 4 + r] = (kv <= qg) ? st[mt][r] * 0.125f : -1e30f;
      }
  } else {
#pragma unroll
    for (int mt = 0; mt < 4; mt++)
#pragma unroll
      for (int r = 0; r < 4; r++) vals[mt * 4 + r] = st[mt][r] * 0.125f;
  }
  float mx = vals[0];
#pragma unroll
  for (int i = 1; i < 16; i++) mx = fmaxf(mx, vals[i]);
  mx = fmaxf(mx, __shfl_xor(mx, 16));
  mx = fmaxf(mx, __shfl_xor(mx, 32));
  float mnew = fmaxf(S.m, mx);
  float alpha = __expf(S.m - mnew);
  float ps = 0.f;
#pragma unroll
  for (int i = 0; i < 16; i++) {
    vals[i] = __expf(vals[i] - mnew);
    ps += vals[i];
  }
  ps += __shfl_xor(ps, 16);
  ps += __shfl_xor(ps, 32);
  S.l = S.l * alpha + ps;
  S.m = mnew;
#pragma unroll
  for (int r = 0; r < 4; r++) {
    float ar = __shfl(alpha, quad * 20 + r);
#pragma unroll
    for (int dt = 0; dt < 4; dt++) S.o[dt][r] *= ar;
  }
  // P[q=l16][kv] bf16 (A-layout for PV), wave-private
#pragma unroll
  for (int mt = 0; mt < 4; mt++) {
    ushort4 pw;
    pw.x = f2bf(vals[mt * 4 + 0]);
    pw.y = f2bf(vals[mt * 4 + 1]);
    pw.z = f2bf(vals[mt * 4 + 2]);
    pw.w = f2bf(vals[mt * 4 + 3]);
    *(ushort4*)&sPw[l16 * AP + mt * 16 + quad * 4] = pw;
  }
#pragma unroll
  for (int kc = 0; kc < 2; kc++) {
    short8 pa = *(const short8*)&sPw[l16 * AP + kc * 32 + quad * 8];
#pragma unroll
    for (int dt = 0; dt < 4; dt++) {
      short8 vb = *(const short8*)&sVt[(dt * 16 + l16) * AP + kc * 32 + quad * 8];
      S.o[dt] = __builtin_amdgcn_mfma_f32_16x16x32_bf16(pa, vb, S.o[dt], 0, 0, 0);
    }
  }
}

__global__ __launch_bounds__(256) void attn_mfma_kernel(
    const unsigned short* __restrict__ qkv, unsigned short* __restrict__ Y) {
  __shared__ short sK[64 * AP];
  __shared__ short sVt[64 * AP];
  __shared__ short sP[4][16 * AP];
  int p = blockIdx.x;  // pair id 0..15: units qtA=p, qtB=31-p (equal total work)
  int hb = blockIdx.y;
  int bb = hb >> 4, h = hb & 15;
  int tid = threadIdx.x, wave = tid >> 6, lane = tid & 63;
  int l16 = lane & 15, quad = lane >> 4;
  int qtA = p, qtB = 31 - p;
  int qbA = qtA * 64 + wave * 16, qbB = qtB * 64 + wave * 16;

  const unsigned short* qrowA = qkv + (size_t)(bb * T_DIM + qbA + l16) * 3072 + h * HD;
  const unsigned short* qrowB = qkv + (size_t)(bb * T_DIM + qbB + l16) * 3072 + h * HD;
  short8 qfA[2], qfB[2];
  qfA[0] = *(const short8*)(qrowA + quad * 8);
  qfA[1] = *(const short8*)(qrowA + 32 + quad * 8);
  qfB[0] = *(const short8*)(qrowB + quad * 8);
  qfB[1] = *(const short8*)(qrowB + 32 + quad * 8);

  AttnState SA, SB;
#pragma unroll
  for (int i = 0; i < 4; i++) {
    SA.o[i] = (f32x4){0.f, 0.f, 0.f, 0.f};
    SB.o[i] = (f32x4){0.f, 0.f, 0.f, 0.f};
  }
  SA.m = -1e30f; SA.l = 0.f; SB.m = -1e30f; SB.l = 0.f;

  const unsigned short* Kbase = qkv + (size_t)bb * T_DIM * 3072 + C_DIM + h * HD;
  const unsigned short* Vbase = Kbase + C_DIM;

  for (int kt = 0; kt <= qtB; kt++) {
    int kv0 = kt * 64;
    if (kt) __syncthreads();
    // ---- stage K rows + V transposed (rotation kills bank conflicts) ----
#pragma unroll
    for (int i = 0; i < 2; i++) {
      int c = tid + i * 256;
      int r = c >> 3, dcg = c & 7, dc = dcg * 8;
      uint4 kx = *(const uint4*)(Kbase + (size_t)(kv0 + r) * 3072 + dc);
      uint4 vx = *(const uint4*)(Vbase + (size_t)(kv0 + r) * 3072 + dc);
      *(uint4*)&sK[r * AP + dc] = kx;
      unsigned short ve[8];
      *(uint4*)ve = vx;
#pragma unroll
      for (int j = 0; j < 8; j++) {
        int jj = (j + r + dcg) & 7;
        sVt[(dc + jj) * AP + r] = (short)ve[jj];
      }
    }
    __syncthreads();

    attn_tile_compute(sK, sVt, sP[wave], qfB, qbB + l16, kv0, kt == qtB, SB, l16, quad);
    if (kt <= qtA)
      attn_tile_compute(sK, sVt, sP[wave], qfA, qbA + l16, kv0, kt == qtA, SA, l16, quad);
  }

  float ilA[4], ilB[4];
#pragma unroll
  for (int r = 0; r < 4; r++) {
    ilA[r] = 1.0f / __shfl(SA.l, quad * 20 + r);
    ilB[r] = 1.0f / __shfl(SB.l, quad * 20 + r);
  }
  unsigned short* YA = Y + (size_t)(bb * T_DIM + qbA) * C_DIM + h * HD;
  unsigned short* YB = Y + (size_t)(bb * T_DIM + qbB) * C_DIM + h * HD;
#pragma unroll
  for (int dt = 0; dt < 4; dt++)
#pragma unroll
    for (int r = 0; r < 4; r++) {
      YA[(size_t)(quad * 4 + r) * C_DIM + dt * 16 + l16] = f2bf(SA.o[dt][r] * ilA[r]);
      YB[(size_t)(quad * 4 + r) * C_DIM + dt * 16 + l16] = f2bf(SB.o[dt][r] * ilB[r]);
    }
}

extern "C" void kernel_launch(void* const* d_in, const int* in_sizes, int n_in,
                              void* d_out, int out_size, void* d_ws, size_t ws_size,
                              hipStream_t stream) {
  const float* x      = (const float*)d_in[0];
  const float* ln1_g  = (const float*)d_in[1];
  const float* ln1_b  = (const float*)d_in[2];
  const float* attn_w = (const float*)d_in[3];
  const float* attn_b = (const float*)d_in[4];
  const float* proj_w = (const float*)d_in[5];
  const float* proj_b = (const float*)d_in[6];
  const float* ln2_g  = (const float*)d_in[7];
  const float* ln2_b  = (const float*)d_in[8];
  const float* fc_w   = (const float*)d_in[9];
  const float* fc_b   = (const float*)d_in[10];
  const float* fc2_w  = (const float*)d_in[11];
  const float* fc2_b  = (const float*)d_in[12];

  char* ws = (char*)d_ws;
  unsigned short* wqkv_t  = (unsigned short*)(ws + 0);          // 6 MB
  unsigned short* wproj_t = (unsigned short*)(ws + 6291456);    // 2 MB
  unsigned short* wfc_t   = (unsigned short*)(ws + 8388608);    // 8 MB
  unsigned short* wfc2_t  = (unsigned short*)(ws + 16777216);   // 8 MB
  unsigned short* xn1     = (unsigned short*)(ws + 25165824);   // 8 MB (reused as xn2)
  unsigned short* qkv     = (unsigned short*)(ws + 33554432);   // 24 MB (32M..56M)
  unsigned short* y       = (unsigned short*)(ws + 58720256);   // 8 MB (56M..64M)
  unsigned short* hmid    = (unsigned short*)(ws + 33554432);   // 32 MB, aliases qkv+y (dead)
  unsigned short* xn2     = xn1;
  float* x1  = (float*)d_out;
  float* out = (float*)d_out;

  dim3 t32x8(32, 8);
  wt_kernel<<<dim3(3072 / 32, 1024 / 32), t32x8, 0, stream>>>(attn_w, wqkv_t, 1024, 3072);
  wt_kernel<<<dim3(1024 / 32, 1024 / 32), t32x8, 0, stream>>>(proj_w, wproj_t, 1024, 1024);
  wt_kernel<<<dim3(4096 / 32, 1024 / 32), t32x8, 0, stream>>>(fc_w, wfc_t, 1024, 4096);
  wt_kernel<<<dim3(1024 / 32, 4096 / 32), t32x8, 0, stream>>>(fc2_w, wfc2_t, 4096, 1024);

  ln_kernel<<<NTOK, 256, 0, stream>>>(x, ln1_g, ln1_b, xn1);
  gemm_bt<0, 1><<<dim3(3072 / 128, NTOK / 128), 256, 0, stream>>>(
      xn1, wqkv_t, attn_b, nullptr, qkv, NTOK, 3072, 1024);
  attn_mfma_kernel<<<dim3(16, 32), 256, 0, stream>>>(qkv, y);
  gemm_bt64<0, 0><<<dim3(1024 / 64, NTOK / 128), 256, 0, stream>>>(
      y, wproj_t, proj_b, x, (void*)x1, NTOK, 1024, 1024);
  ln_kernel<<<NTOK, 256, 0, stream>>>(x1, ln2_g, ln2_b, xn2);
  gemm_bt<1, 1><<<dim3(4096 / 128, NTOK / 128), 256, 0, stream>>>(
      xn2, wfc_t, fc_b, nullptr, hmid, NTOK, 4096, 1024);
  gemm_bt64<0, 0><<<dim3(1024 / 64, NTOK / 128), 256, 0, stream>>>(
      hmid, wfc2_t, fc2_b, x1, (void*)out, NTOK, 1024, 4096);
}